// Round 3
// baseline (469.442 us; speedup 1.0000x reference)
//
#include <hip/hip_runtime.h>
#include <hip/hip_bf16.h>
#include <stdint.h>

#define N_NODES 100000
#define IN_F    512
#define OUT_F   256
#define N_EDGES 1600000

typedef __attribute__((ext_vector_type(4))) float f32x4;
typedef __attribute__((ext_vector_type(8))) short bf16x8;
typedef __attribute__((ext_vector_type(4))) uint32_t u32x4;

#define BM 128
#define BN 128
#define BK 32
#define LDW (BK + 8)   // 80B row stride, 16B-aligned for b128 LDS ops

#define SCAN_CHUNK 4096
#define NCHUNKS ((N_NODES + SCAN_CHUNK - 1) / SCAN_CHUNK)   // 25

__device__ __forceinline__ float bf2f(uint16_t u) {
    union { uint32_t i; float f; } c; c.i = ((uint32_t)u) << 16; return c.f;
}
__device__ __forceinline__ uint16_t f2bf(float f) {
    union { float f; uint32_t i; } c; c.f = f;
    uint32_t x = c.i;
    return (uint16_t)((x + 0x7FFFu + ((x >> 16) & 1u)) >> 16);  // RNE
}
// packed f32 pair -> 2x bf16 (RNE) in one HW op; lo16 = bf16(a), hi16 = bf16(b)
__device__ __forceinline__ uint32_t cvt_pk_bf16(float a, float b) {
    uint32_t r;
    asm("v_cvt_pk_bf16_f32 %0, %1, %2" : "=v"(r) : "v"(a), "v"(b));
    return r;
}

// ---------------- GEMM: h = bf16(feat @ W^T + b) ----------------
__global__ __launch_bounds__(256) void gcn_gemm_kernel(
    const float* __restrict__ feat, const float* __restrict__ W,
    const float* __restrict__ bias, uint16_t* __restrict__ h)
{
    __shared__ uint16_t At[BM][LDW];
    __shared__ uint16_t Bt[BN][LDW];

    const int bid = blockIdx.x;
    const int mt = bid >> 1;
    const int nt = bid & 1;
    const int m0 = mt * BM;
    const int n0 = nt * BN;

    const int t    = threadIdx.x;
    const int wid  = t >> 6;
    const int lane = t & 63;
    const int wr   = wid >> 1, wc = wid & 1;
    const int lrow = lane & 15;
    const int kg   = lane >> 4;

    f32x4 acc[4][4] = {};

    const int srow  = t >> 1;
    const int shalf = t & 1;
    const bool arow_ok = (m0 + srow) < N_NODES;

    const float* gA = feat + (size_t)(m0 + srow) * IN_F + shalf * 16;
    const float* gB = W    + (size_t)(n0 + srow) * IN_F + shalf * 16;

    const f32x4 zero = {0.f, 0.f, 0.f, 0.f};

    // ---- prologue: load + stage kt=0 ----
    f32x4 pa[4], pb[4];
    {
        const f32x4* pA = (const f32x4*)gA;
        const f32x4* pB = (const f32x4*)gB;
        #pragma unroll
        for (int i = 0; i < 4; ++i) {
            pa[i] = arow_ok ? pA[i] : zero;
            pb[i] = pB[i];
        }
        u32x4 ca, cb;
        #pragma unroll
        for (int i = 0; i < 2; ++i) {
            ca[2*i]   = cvt_pk_bf16(pa[i][0], pa[i][1]);
            ca[2*i+1] = cvt_pk_bf16(pa[i][2], pa[i][3]);
            cb[2*i]   = cvt_pk_bf16(pb[i][0], pb[i][1]);
            cb[2*i+1] = cvt_pk_bf16(pb[i][2], pb[i][3]);
        }
        *(u32x4*)&At[srow][shalf*16] = ca;
        *(u32x4*)&Bt[srow][shalf*16] = cb;
        #pragma unroll
        for (int i = 0; i < 2; ++i) {
            ca[2*i]   = cvt_pk_bf16(pa[2+i][0], pa[2+i][1]);
            ca[2*i+1] = cvt_pk_bf16(pa[2+i][2], pa[2+i][3]);
            cb[2*i]   = cvt_pk_bf16(pb[2+i][0], pb[2+i][1]);
            cb[2*i+1] = cvt_pk_bf16(pb[2+i][2], pb[2+i][3]);
        }
        *(u32x4*)&At[srow][shalf*16 + 8] = ca;
        *(u32x4*)&Bt[srow][shalf*16 + 8] = cb;
    }
    __syncthreads();

    for (int kt = 0; kt < IN_F / BK; ++kt) {
        const bool more = (kt + 1) < (IN_F / BK);
        // ---- issue prefetch of kt+1 (vmcnt wait lands after the MFMAs) ----
        f32x4 na[4], nb[4];
        if (more) {
            const f32x4* pA = (const f32x4*)(gA + (kt + 1) * BK);
            const f32x4* pB = (const f32x4*)(gB + (kt + 1) * BK);
            #pragma unroll
            for (int i = 0; i < 4; ++i) {
                na[i] = arow_ok ? pA[i] : zero;
                nb[i] = pB[i];
            }
        }
        // ---- fragments + MFMA on current LDS tile ----
        bf16x8 af[4], bfr[4];
        #pragma unroll
        for (int m = 0; m < 4; ++m)
            af[m] = *(const bf16x8*)&At[wr*64 + m*16 + lrow][kg*8];
        #pragma unroll
        for (int n = 0; n < 4; ++n)
            bfr[n] = *(const bf16x8*)&Bt[wc*64 + n*16 + lrow][kg*8];
        #pragma unroll
        for (int m = 0; m < 4; ++m)
            #pragma unroll
            for (int n = 0; n < 4; ++n)
                acc[m][n] = __builtin_amdgcn_mfma_f32_16x16x32_bf16(
                    af[m], bfr[n], acc[m][n], 0, 0, 0);
        __syncthreads();
        // ---- convert + store kt+1 into LDS ----
        if (more) {
            u32x4 ca, cb;
            #pragma unroll
            for (int i = 0; i < 2; ++i) {
                ca[2*i]   = cvt_pk_bf16(na[i][0], na[i][1]);
                ca[2*i+1] = cvt_pk_bf16(na[i][2], na[i][3]);
                cb[2*i]   = cvt_pk_bf16(nb[i][0], nb[i][1]);
                cb[2*i+1] = cvt_pk_bf16(nb[i][2], nb[i][3]);
            }
            *(u32x4*)&At[srow][shalf*16] = ca;
            *(u32x4*)&Bt[srow][shalf*16] = cb;
            #pragma unroll
            for (int i = 0; i < 2; ++i) {
                ca[2*i]   = cvt_pk_bf16(na[2+i][0], na[2+i][1]);
                ca[2*i+1] = cvt_pk_bf16(na[2+i][2], na[2+i][3]);
                cb[2*i]   = cvt_pk_bf16(nb[2+i][0], nb[2+i][1]);
                cb[2*i+1] = cvt_pk_bf16(nb[2+i][2], nb[2+i][3]);
            }
            *(u32x4*)&At[srow][shalf*16 + 8] = ca;
            *(u32x4*)&Bt[srow][shalf*16 + 8] = cb;
            __syncthreads();
        }
    }

    // ---- epilogue: bias + bf16 store ----
    #pragma unroll
    for (int n = 0; n < 4; ++n) {
        const int col = n0 + wc*64 + n*16 + lrow;
        const float bv = bias[col];
        #pragma unroll
        for (int m = 0; m < 4; ++m) {
            #pragma unroll
            for (int j = 0; j < 4; ++j) {
                const int row = m0 + wr*64 + m*16 + kg*4 + j;
                if (row < N_NODES)
                    h[(size_t)row * OUT_F + col] = f2bf(acc[m][n][j] + bv);
            }
        }
    }
}

// ---------------- CSR build ----------------
__global__ __launch_bounds__(256) void hist_kernel(
    const int* __restrict__ dst, int* __restrict__ deg)
{
    const int e = blockIdx.x * 256 + threadIdx.x;
    if (e < N_EDGES) atomicAdd(&deg[dst[e]], 1);
}

__global__ __launch_bounds__(256) void chunk_reduce_kernel(
    const int* __restrict__ deg, int* __restrict__ chunkSum)
{
    __shared__ int red[256];
    const int b = blockIdx.x, t = threadIdx.x;
    const int base = b * SCAN_CHUNK;
    int s = 0;
    #pragma unroll
    for (int i = 0; i < 16; ++i) {
        const int idx = base + t * 16 + i;
        s += (idx < N_NODES) ? deg[idx] : 0;
    }
    red[t] = s;
    __syncthreads();
    for (int off = 128; off > 0; off >>= 1) {
        if (t < off) red[t] += red[t + off];
        __syncthreads();
    }
    if (t == 0) chunkSum[b] = red[0];
}

__global__ void scan_chunksums_kernel(const int* __restrict__ chunkSum,
                                      int* __restrict__ chunkOff)
{
    if (threadIdx.x == 0 && blockIdx.x == 0) {
        int acc = 0;
        for (int i = 0; i < NCHUNKS; ++i) { chunkOff[i] = acc; acc += chunkSum[i]; }
    }
}

__global__ __launch_bounds__(256) void chunk_scan_kernel(
    const int* __restrict__ deg, const int* __restrict__ chunkOff,
    int* __restrict__ start, int* __restrict__ cursor)
{
    __shared__ int tsum[256];
    const int b = blockIdx.x, t = threadIdx.x;
    const int base = b * SCAN_CHUNK;
    int vals[16];
    int s = 0;
    #pragma unroll
    for (int i = 0; i < 16; ++i) {
        const int idx = base + t * 16 + i;
        const int v = (idx < N_NODES) ? deg[idx] : 0;
        vals[i] = s;
        s += v;
    }
    int x = s;
    tsum[t] = x;
    __syncthreads();
    #pragma unroll
    for (int off = 1; off < 256; off <<= 1) {
        const int y = (t >= off) ? tsum[t - off] : 0;
        __syncthreads();
        x += y;
        tsum[t] = x;
        __syncthreads();
    }
    const int thread_off = chunkOff[b] + (t == 0 ? 0 : tsum[t - 1]);
    #pragma unroll
    for (int i = 0; i < 16; ++i) {
        const int idx = base + t * 16 + i;
        if (idx < N_NODES) {
            const int st = thread_off + vals[i];
            start[idx] = st;
            cursor[idx] = st;
        }
    }
}

__global__ __launch_bounds__(256) void csr_fill_kernel(
    const int* __restrict__ src, const int* __restrict__ dst,
    int* __restrict__ cursor, int* __restrict__ csr_src)
{
    const int e = blockIdx.x * 256 + threadIdx.x;
    if (e < N_EDGES) {
        const int d = dst[e];
        const int p = atomicAdd(&cursor[d], 1);
        csr_src[p] = src[e];
    }
}

// ---------------- gather: one wave per dst node, atomic-free ----------------
__global__ __launch_bounds__(256) void gcn_gather_kernel(
    const uint16_t* __restrict__ h, const int* __restrict__ start,
    const int* __restrict__ csr_src, float* __restrict__ out)
{
    const int n = blockIdx.x * 4 + (threadIdx.x >> 6);
    if (n >= N_NODES) return;
    const int lane = threadIdx.x & 63;
    const int beg = start[n];
    const int end = (n == N_NODES - 1) ? N_EDGES : start[n + 1];

    float a0 = 0.f, a1 = 0.f, a2 = 0.f, a3 = 0.f;
    int j = beg;
    for (; j + 1 < end; j += 2) {
        const int s0 = csr_src[j];
        const int s1 = csr_src[j + 1];
        const ushort4 v0 = *((const ushort4*)(h + (size_t)s0 * OUT_F) + lane);
        const ushort4 v1 = *((const ushort4*)(h + (size_t)s1 * OUT_F) + lane);
        a0 += bf2f(v0.x); a1 += bf2f(v0.y); a2 += bf2f(v0.z); a3 += bf2f(v0.w);
        a0 += bf2f(v1.x); a1 += bf2f(v1.y); a2 += bf2f(v1.z); a3 += bf2f(v1.w);
    }
    if (j < end) {
        const int s0 = csr_src[j];
        const ushort4 v0 = *((const ushort4*)(h + (size_t)s0 * OUT_F) + lane);
        a0 += bf2f(v0.x); a1 += bf2f(v0.y); a2 += bf2f(v0.z); a3 += bf2f(v0.w);
    }
    f32x4 o; o[0] = a0; o[1] = a1; o[2] = a2; o[3] = a3;
    *((f32x4*)(out + (size_t)n * OUT_F) + lane) = o;
}

// ---------------- fallback atomic scatter (small ws) ----------------
__global__ __launch_bounds__(256) void gcn_scatter_kernel(
    const uint16_t* __restrict__ h, const int* __restrict__ src,
    const int* __restrict__ dst, float* __restrict__ out)
{
    const int e = (blockIdx.x << 2) | (threadIdx.x >> 6);
    if (e >= N_EDGES) return;
    const int lane = threadIdx.x & 63;
    const int s = src[e];
    const int d = dst[e];
    const ushort4 v = *((const ushort4*)(h + (size_t)s * OUT_F) + lane);
    float* op = out + (size_t)d * OUT_F + (lane << 2);
    unsafeAtomicAdd(op + 0, bf2f(v.x));
    unsafeAtomicAdd(op + 1, bf2f(v.y));
    unsafeAtomicAdd(op + 2, bf2f(v.z));
    unsafeAtomicAdd(op + 3, bf2f(v.w));
}

static inline size_t align256(size_t x) { return (x + 255) & ~(size_t)255; }

extern "C" void kernel_launch(void* const* d_in, const int* in_sizes, int n_in,
                              void* d_out, int out_size, void* d_ws, size_t ws_size,
                              hipStream_t stream) {
    const float* feat = (const float*)d_in[0];
    const float* W    = (const float*)d_in[1];
    const float* bias = (const float*)d_in[2];
    const int*   src  = (const int*)d_in[3];
    const int*   dst  = (const int*)d_in[4];
    float*       out  = (float*)d_out;

    char* ws = (char*)d_ws;
    size_t off = 0;
    uint16_t* h = (uint16_t*)(ws + off);        off = align256(off + (size_t)N_NODES * OUT_F * 2);
    int* deg      = (int*)(ws + off);           off = align256(off + (size_t)N_NODES * 4);
    int* start    = (int*)(ws + off);           off = align256(off + (size_t)N_NODES * 4);
    int* cursor   = (int*)(ws + off);           off = align256(off + (size_t)N_NODES * 4);
    int* chunkSum = (int*)(ws + off);           off = align256(off + (size_t)NCHUNKS * 4);
    int* chunkOff = (int*)(ws + off);           off = align256(off + (size_t)NCHUNKS * 4);
    int* csr_src  = (int*)(ws + off);           off = align256(off + (size_t)N_EDGES * 4);
    const bool csr_ok = (off <= ws_size);

    const int mtiles = (N_NODES + BM - 1) / BM;  // 782
    gcn_gemm_kernel<<<mtiles * 2, 256, 0, stream>>>(feat, W, bias, h);

    if (csr_ok) {
        hipMemsetAsync(deg, 0, (size_t)N_NODES * 4, stream);
        const int eblocks = (N_EDGES + 255) / 256;  // 6250
        hist_kernel<<<eblocks, 256, 0, stream>>>(dst, deg);
        chunk_reduce_kernel<<<NCHUNKS, 256, 0, stream>>>(deg, chunkSum);
        scan_chunksums_kernel<<<1, 64, 0, stream>>>(chunkSum, chunkOff);
        chunk_scan_kernel<<<NCHUNKS, 256, 0, stream>>>(deg, chunkOff, start, cursor);
        csr_fill_kernel<<<eblocks, 256, 0, stream>>>(src, dst, cursor, csr_src);
        gcn_gather_kernel<<<(N_NODES + 3) / 4, 256, 0, stream>>>(h, start, csr_src, out);
    } else {
        hipMemsetAsync(out, 0, (size_t)out_size * sizeof(float), stream);
        gcn_scatter_kernel<<<(N_EDGES + 3) / 4, 256, 0, stream>>>(h, src, dst, out);
    }
}

// Round 4
// 451.486 us; speedup vs baseline: 1.0398x; 1.0398x over previous
//
#include <hip/hip_runtime.h>
#include <hip/hip_bf16.h>
#include <stdint.h>

#define N_NODES 100000
#define IN_F    512
#define OUT_F   256
#define N_EDGES 1600000

typedef __attribute__((ext_vector_type(4))) float f32x4;
typedef __attribute__((ext_vector_type(8))) short bf16x8;
typedef __attribute__((ext_vector_type(4))) uint32_t u32x4;

#define BM 128
#define BK 32
#define KT_TILES (IN_F / BK)     // 16
#define LDW (BK + 8)             // 80 B row stride -> 2-way bank aliasing (free)
#define WFRAG_KT_STRIDE (16 * 16 * 32)   // 8192 elems per kt slab

#define SCAN_CHUNK 4096
#define NCHUNKS ((N_NODES + SCAN_CHUNK - 1) / SCAN_CHUNK)   // 25

__device__ __forceinline__ float bf2f(uint16_t u) {
    union { uint32_t i; float f; } c; c.i = ((uint32_t)u) << 16; return c.f;
}
__device__ __forceinline__ uint16_t f2bf(float f) {
    union { float f; uint32_t i; } c; c.f = f;
    uint32_t x = c.i;
    return (uint16_t)((x + 0x7FFFu + ((x >> 16) & 1u)) >> 16);  // RNE
}
__device__ __forceinline__ uint32_t cvt_pk_bf16(float a, float b) {
    uint32_t r;
    asm("v_cvt_pk_bf16_f32 %0, %1, %2" : "=v"(r) : "v"(a), "v"(b));
    return r;
}

// ---------------- W -> bf16 fragment-order ----------------
// w_frag[((kt*16 + cg)*16 + lrow)*32 + kg*8 + j] = bf16(W[cg*16+lrow][kt*32+kg*8+j])
__global__ __launch_bounds__(256) void w_frag_kernel(
    const float* __restrict__ W, uint16_t* __restrict__ w_frag)
{
    const int gid = blockIdx.x * 256 + threadIdx.x;   // 16384 groups of 8 elems
    if (gid >= 16384) return;
    const int kg = gid & 3, lrow = (gid >> 2) & 15, cg = (gid >> 6) & 15, kt = gid >> 10;
    const float* s = W + (size_t)(cg * 16 + lrow) * IN_F + kt * 32 + kg * 8;
    const f32x4 v0 = *(const f32x4*)s;
    const f32x4 v1 = *(const f32x4*)(s + 4);
    u32x4 c;
    c[0] = cvt_pk_bf16(v0[0], v0[1]);
    c[1] = cvt_pk_bf16(v0[2], v0[3]);
    c[2] = cvt_pk_bf16(v1[0], v1[1]);
    c[3] = cvt_pk_bf16(v1[2], v1[3]);
    *(u32x4*)(w_frag + (size_t)gid * 8) = c;
}

__device__ __forceinline__ void cvt_write_tile(
    uint16_t (*Ab)[LDW], int srow, int shalf, const f32x4* ar)
{
    u32x4 c0, c1;
    c0[0] = cvt_pk_bf16(ar[0][0], ar[0][1]); c0[1] = cvt_pk_bf16(ar[0][2], ar[0][3]);
    c0[2] = cvt_pk_bf16(ar[1][0], ar[1][1]); c0[3] = cvt_pk_bf16(ar[1][2], ar[1][3]);
    c1[0] = cvt_pk_bf16(ar[2][0], ar[2][1]); c1[1] = cvt_pk_bf16(ar[2][2], ar[2][3]);
    c1[2] = cvt_pk_bf16(ar[3][0], ar[3][1]); c1[3] = cvt_pk_bf16(ar[3][2], ar[3][3]);
    *(u32x4*)&Ab[srow][shalf * 16]     = c0;
    *(u32x4*)&Ab[srow][shalf * 16 + 8] = c1;
}

// ---------------- GEMM: h = bf16(feat @ W^T + b) ----------------
// A: LDS double-buffered, loads issued 2 tiles ahead. B: fragments direct from
// L2-resident w_frag, prefetched 1 tile ahead. One barrier per kt.
__global__ __launch_bounds__(256) void gcn_gemm_kernel(
    const float* __restrict__ feat, const uint16_t* __restrict__ w_frag,
    const float* __restrict__ bias, uint16_t* __restrict__ h)
{
    __shared__ uint16_t At[2][BM][LDW];   // 20.5 KB

    const int bid = blockIdx.x;
    const int mt = bid >> 1;
    const int nt = bid & 1;
    const int m0 = mt * BM;

    const int t    = threadIdx.x;
    const int wid  = t >> 6;
    const int lane = t & 63;
    const int wr   = wid >> 1, wc = wid & 1;
    const int lrow = lane & 15;
    const int kg   = lane >> 4;

    const int srow  = t >> 1;
    const int shalf = t & 1;
    const bool arow_ok = (m0 + srow) < N_NODES;
    const float* gA = feat + (size_t)(m0 + srow) * IN_F + shalf * 16;
    const f32x4 zero = {0.f, 0.f, 0.f, 0.f};

    f32x4 acc[4][4] = {};

    // per-wave B fragment base pointers (kt advances by WFRAG_KT_STRIDE)
    const uint16_t* wf[4];
    #pragma unroll
    for (int n = 0; n < 4; ++n) {
        const int cg = nt * 8 + wc * 4 + n;
        wf[n] = w_frag + ((size_t)cg * 16 + lrow) * 32 + kg * 8;
    }

    f32x4 ar[4];
    bf16x8 bcur[4], bnext[4];

    // ---- prologue ----
    #pragma unroll
    for (int i = 0; i < 4; ++i) ar[i] = arow_ok ? ((const f32x4*)gA)[i] : zero;
    #pragma unroll
    for (int n = 0; n < 4; ++n) bcur[n] = *(const bf16x8*)(wf[n]);
    cvt_write_tile(At[0], srow, shalf, ar);                 // tile 0 -> buf0
    #pragma unroll
    for (int i = 0; i < 4; ++i) ar[i] = arow_ok ? ((const f32x4*)(gA + BK))[i] : zero;  // tile 1 in flight
    #pragma unroll
    for (int n = 0; n < 4; ++n) bnext[n] = *(const bf16x8*)(wf[n] + WFRAG_KT_STRIDE);
    __syncthreads();

    #pragma unroll
    for (int kt = 0; kt < KT_TILES; ++kt) {
        bf16x8 af[4];
        #pragma unroll
        for (int m = 0; m < 4; ++m)
            af[m] = *(const bf16x8*)&At[kt & 1][wr * 64 + m * 16 + lrow][kg * 8];
        #pragma unroll
        for (int m = 0; m < 4; ++m)
            #pragma unroll
            for (int n = 0; n < 4; ++n)
                acc[m][n] = __builtin_amdgcn_mfma_f32_16x16x32_bf16(
                    af[m], bcur[n], acc[m][n], 0, 0, 0);
        if (kt + 1 < KT_TILES) {
            cvt_write_tile(At[(kt + 1) & 1], srow, shalf, ar);   // waits tile kt+1 loads
            #pragma unroll
            for (int n = 0; n < 4; ++n) bcur[n] = bnext[n];
            if (kt + 2 < KT_TILES) {
                #pragma unroll
                for (int i = 0; i < 4; ++i)
                    ar[i] = arow_ok ? ((const f32x4*)(gA + (kt + 2) * BK))[i] : zero;
                #pragma unroll
                for (int n = 0; n < 4; ++n)
                    bnext[n] = *(const bf16x8*)(wf[n] + (size_t)(kt + 2) * WFRAG_KT_STRIDE);
            }
            __syncthreads();
        }
    }

    // ---- epilogue: bias + bf16 store ----
    #pragma unroll
    for (int n = 0; n < 4; ++n) {
        const int col = nt * 128 + wc * 64 + n * 16 + lrow;
        const float bv = bias[col];
        #pragma unroll
        for (int m = 0; m < 4; ++m) {
            #pragma unroll
            for (int j = 0; j < 4; ++j) {
                const int row = m0 + wr * 64 + m * 16 + kg * 4 + j;
                if (row < N_NODES)
                    h[(size_t)row * OUT_F + col] = f2bf(acc[m][n][j] + bv);
            }
        }
    }
}

// ---------------- CSR build ----------------
__global__ __launch_bounds__(256) void hist_kernel(
    const int* __restrict__ dst, int* __restrict__ deg)
{
    const int e = blockIdx.x * 256 + threadIdx.x;
    if (e < N_EDGES) atomicAdd(&deg[dst[e]], 1);
}

__global__ __launch_bounds__(256) void chunk_reduce_kernel(
    const int* __restrict__ deg, int* __restrict__ chunkSum)
{
    __shared__ int red[256];
    const int b = blockIdx.x, t = threadIdx.x;
    const int base = b * SCAN_CHUNK;
    int s = 0;
    #pragma unroll
    for (int i = 0; i < 16; ++i) {
        const int idx = base + t * 16 + i;
        s += (idx < N_NODES) ? deg[idx] : 0;
    }
    red[t] = s;
    __syncthreads();
    for (int off = 128; off > 0; off >>= 1) {
        if (t < off) red[t] += red[t + off];
        __syncthreads();
    }
    if (t == 0) chunkSum[b] = red[0];
}

__global__ void scan_chunksums_kernel(const int* __restrict__ chunkSum,
                                      int* __restrict__ chunkOff)
{
    if (threadIdx.x == 0 && blockIdx.x == 0) {
        int acc = 0;
        for (int i = 0; i < NCHUNKS; ++i) { chunkOff[i] = acc; acc += chunkSum[i]; }
    }
}

__global__ __launch_bounds__(256) void chunk_scan_kernel(
    const int* __restrict__ deg, const int* __restrict__ chunkOff,
    int* __restrict__ start, int* __restrict__ cursor)
{
    __shared__ int tsum[256];
    const int b = blockIdx.x, t = threadIdx.x;
    const int base = b * SCAN_CHUNK;
    int vals[16];
    int s = 0;
    #pragma unroll
    for (int i = 0; i < 16; ++i) {
        const int idx = base + t * 16 + i;
        const int v = (idx < N_NODES) ? deg[idx] : 0;
        vals[i] = s;
        s += v;
    }
    int x = s;
    tsum[t] = x;
    __syncthreads();
    #pragma unroll
    for (int off = 1; off < 256; off <<= 1) {
        const int y = (t >= off) ? tsum[t - off] : 0;
        __syncthreads();
        x += y;
        tsum[t] = x;
        __syncthreads();
    }
    const int thread_off = chunkOff[b] + (t == 0 ? 0 : tsum[t - 1]);
    #pragma unroll
    for (int i = 0; i < 16; ++i) {
        const int idx = base + t * 16 + i;
        if (idx < N_NODES) {
            const int st = thread_off + vals[i];
            start[idx] = st;
            cursor[idx] = st;
        }
    }
}

__global__ __launch_bounds__(256) void csr_fill_kernel(
    const int* __restrict__ src, const int* __restrict__ dst,
    int* __restrict__ cursor, int* __restrict__ csr_src)
{
    const int e = blockIdx.x * 256 + threadIdx.x;
    if (e < N_EDGES) {
        const int d = dst[e];
        const int p = atomicAdd(&cursor[d], 1);
        csr_src[p] = src[e];
    }
}

// ---------------- gather: one wave per dst node, atomic-free ----------------
__global__ __launch_bounds__(256) void gcn_gather_kernel(
    const uint16_t* __restrict__ h, const int* __restrict__ start,
    const int* __restrict__ csr_src, float* __restrict__ out)
{
    const int n = blockIdx.x * 4 + (threadIdx.x >> 6);
    if (n >= N_NODES) return;
    const int lane = threadIdx.x & 63;
    const int beg = start[n];
    const int end = (n == N_NODES - 1) ? N_EDGES : start[n + 1];

    float a0 = 0.f, a1 = 0.f, a2 = 0.f, a3 = 0.f;
    int j = beg;
    for (; j + 1 < end; j += 2) {
        const int s0 = csr_src[j];
        const int s1 = csr_src[j + 1];
        const ushort4 v0 = *((const ushort4*)(h + (size_t)s0 * OUT_F) + lane);
        const ushort4 v1 = *((const ushort4*)(h + (size_t)s1 * OUT_F) + lane);
        a0 += bf2f(v0.x); a1 += bf2f(v0.y); a2 += bf2f(v0.z); a3 += bf2f(v0.w);
        a0 += bf2f(v1.x); a1 += bf2f(v1.y); a2 += bf2f(v1.z); a3 += bf2f(v1.w);
    }
    if (j < end) {
        const int s0 = csr_src[j];
        const ushort4 v0 = *((const ushort4*)(h + (size_t)s0 * OUT_F) + lane);
        a0 += bf2f(v0.x); a1 += bf2f(v0.y); a2 += bf2f(v0.z); a3 += bf2f(v0.w);
    }
    f32x4 o; o[0] = a0; o[1] = a1; o[2] = a2; o[3] = a3;
    *((f32x4*)(out + (size_t)n * OUT_F) + lane) = o;
}

// ---------------- fallback atomic scatter (small ws) ----------------
__global__ __launch_bounds__(256) void gcn_scatter_kernel(
    const uint16_t* __restrict__ h, const int* __restrict__ src,
    const int* __restrict__ dst, float* __restrict__ out)
{
    const int e = (blockIdx.x << 2) | (threadIdx.x >> 6);
    if (e >= N_EDGES) return;
    const int lane = threadIdx.x & 63;
    const int s = src[e];
    const int d = dst[e];
    const ushort4 v = *((const ushort4*)(h + (size_t)s * OUT_F) + lane);
    float* op = out + (size_t)d * OUT_F + (lane << 2);
    unsafeAtomicAdd(op + 0, bf2f(v.x));
    unsafeAtomicAdd(op + 1, bf2f(v.y));
    unsafeAtomicAdd(op + 2, bf2f(v.z));
    unsafeAtomicAdd(op + 3, bf2f(v.w));
}

static inline size_t align256(size_t x) { return (x + 255) & ~(size_t)255; }

extern "C" void kernel_launch(void* const* d_in, const int* in_sizes, int n_in,
                              void* d_out, int out_size, void* d_ws, size_t ws_size,
                              hipStream_t stream) {
    const float* feat = (const float*)d_in[0];
    const float* W    = (const float*)d_in[1];
    const float* bias = (const float*)d_in[2];
    const int*   src  = (const int*)d_in[3];
    const int*   dst  = (const int*)d_in[4];
    float*       out  = (float*)d_out;

    char* ws = (char*)d_ws;
    size_t off = 0;
    uint16_t* h      = (uint16_t*)(ws + off);   off = align256(off + (size_t)N_NODES * OUT_F * 2);
    uint16_t* w_frag = (uint16_t*)(ws + off);   off = align256(off + (size_t)OUT_F * IN_F * 2);
    int* deg      = (int*)(ws + off);           off = align256(off + (size_t)N_NODES * 4);
    int* start    = (int*)(ws + off);           off = align256(off + (size_t)N_NODES * 4);
    int* cursor   = (int*)(ws + off);           off = align256(off + (size_t)N_NODES * 4);
    int* chunkSum = (int*)(ws + off);           off = align256(off + (size_t)NCHUNKS * 4);
    int* chunkOff = (int*)(ws + off);           off = align256(off + (size_t)NCHUNKS * 4);
    int* csr_src  = (int*)(ws + off);           off = align256(off + (size_t)N_EDGES * 4);
    const bool csr_ok = (off <= ws_size);

    const int mtiles = (N_NODES + BM - 1) / BM;  // 782

    w_frag_kernel<<<64, 256, 0, stream>>>(W, w_frag);
    gcn_gemm_kernel<<<mtiles * 2, 256, 0, stream>>>(feat, w_frag, bias, h);

    if (csr_ok) {
        hipMemsetAsync(deg, 0, (size_t)N_NODES * 4, stream);
        const int eblocks = (N_EDGES + 255) / 256;  // 6250
        hist_kernel<<<eblocks, 256, 0, stream>>>(dst, deg);
        chunk_reduce_kernel<<<NCHUNKS, 256, 0, stream>>>(deg, chunkSum);
        scan_chunksums_kernel<<<1, 64, 0, stream>>>(chunkSum, chunkOff);
        chunk_scan_kernel<<<NCHUNKS, 256, 0, stream>>>(deg, chunkOff, start, cursor);
        csr_fill_kernel<<<eblocks, 256, 0, stream>>>(src, dst, cursor, csr_src);
        gcn_gather_kernel<<<(N_NODES + 3) / 4, 256, 0, stream>>>(h, start, csr_src, out);
    } else {
        hipMemsetAsync(out, 0, (size_t)out_size * sizeof(float), stream);
        gcn_scatter_kernel<<<(N_EDGES + 3) / 4, 256, 0, stream>>>(h, src, dst, out);
    }
}